// Round 11
// baseline (119730.615 us; speedup 1.0000x reference)
//
#include <hip/hip_runtime.h>
#include <cstddef>

// ---------------------------------------------------------------------------
// 3-layer LSTM (1->32->32->3), T=200000 sequential steps.
// TWO-wave fused pipeline on one CU, 8 steps per barrier epoch:
//   wave 0: layer 0 recurrence (+x staging)  AND  layer 2 + output
//           (two independent serial chains, interleaved by the scheduler)
//   wave 1: layer 1 complete (U-dot + V-dot + cell) -- U FMAs hide in the
//           V-chain's latency stalls; no u1s cross-wave handoff anymore.
// Cross-wave edges (epoch-lagged, parity-buffered): h0 (w0->w1, lag 1),
// h1 (w1->w0, lag 2 for L2). One s_barrier per 8 steps, lgkmcnt-only drain.
// NO intra-epoch fences: DS ops from one wave execute in order, and the
// compiler's automatic s_waitcnt covers read-data hazards.
// Per-gate arithmetic bit-identical to R9 (same strands, same fast_gate).
// ---------------------------------------------------------------------------

#define XCH 256  // x chunk elements
#define SPB 8    // steps per barrier epoch (SPB*32 = 256 = XCH)

typedef float f32x2 __attribute__((ext_vector_type(2)));

__device__ __forceinline__ f32x2 pk_fma(f32x2 a, f32x2 b, f32x2 c) {
    f32x2 d;
    asm("v_pk_fma_f32 %0, %1, %2, %3" : "=v"(d) : "v"(a), "v"(b), "v"(c));
    return d;
}
__device__ __forceinline__ f32x2 lds_ld2(const float* p) {
    f32x2 v; __builtin_memcpy(&v, p, sizeof(f32x2)); return v;
}

__device__ __forceinline__ float v_exp2(float x) {
    float r; asm("v_exp_f32 %0, %1" : "=v"(r) : "v"(x)); return r;
}
__device__ __forceinline__ float v_rcp(float x) {
    float r; asm("v_rcp_f32 %0, %1" : "=v"(r) : "v"(x)); return r;
}
// act = m / (1 + exp(z)) + a0, residual-compensated v_exp + Newton v_rcp.
__device__ __forceinline__ float fast_gate(float z, float m, float a0) {
    const float L2E    = 1.44269502162933349609375f;
    const float L2E_LO = 1.9259629911e-8f;
    const float LN2    = 0.69314718055994530942f;
    const float t  = z * L2E;
    const float r  = fmaf(z, L2E, -t);
    const float dt = fmaf(z, L2E_LO, r);
    const float e0 = v_exp2(t);
    const float e  = fmaf(e0, dt * LN2, e0);
    const float den = 1.0f + e;
    const float r0 = v_rcp(den);
    const float er = fmaf(-den, r0, 1.0f);
    const float r1 = fmaf(r0, er, r0);
    return fmaf(m, r1, a0);
}
__device__ __forceinline__ float fast_tanh(float c) {
    return fast_gate(-2.0f * c, 2.0f, -1.0f);
}

// neighbor exchange (lane ^ 1): quad_perm DPP (VALU).
__device__ __forceinline__ float swap1(float v) {
    return __shfl_xor(v, 1);
}

// epoch barrier WITHOUT vmcnt drain (out-stores keep flying)
__device__ __forceinline__ void pipe_barrier() {
    asm volatile("s_waitcnt lgkmcnt(0)\n\ts_barrier" ::: "memory");
}

__global__ __launch_bounds__(128, 1)
void lstm3_fuse2_kernel(const float* __restrict__ x,
                        const float* __restrict__ Wih0, const float* __restrict__ Whh0,
                        const float* __restrict__ bih0, const float* __restrict__ bhh0,
                        const float* __restrict__ Wih1, const float* __restrict__ Whh1,
                        const float* __restrict__ bih1, const float* __restrict__ bhh1,
                        const float* __restrict__ pre_h0, const float* __restrict__ pre_c0,
                        const float* __restrict__ Wih2, const float* __restrict__ Whh2,
                        const float* __restrict__ bih2, const float* __restrict__ bhh2,
                        const float* __restrict__ post_h0, const float* __restrict__ post_c0,
                        float* __restrict__ out, int T)
{
    const int tid = threadIdx.x;
    const int w   = tid >> 6;     // 0 = L0+L2+out+x, 1 = L1
    const int l   = tid & 63;

    __shared__ __align__(16) float h0s[2][SPB][32];  // [time-epoch parity][step][cell]
    __shared__ __align__(16) float h1s[2][SPB][32];
    __shared__ __align__(16) float xbuf[2][XCH];

    const int E0   = (T + SPB - 1) / SPB;   // L0 epochs
    const int Etot = E0 + 2;

    if (w == 0) {
        // ========== wave 0: layer 0 (xor-1 layout) + layer 2 + x ==========
        const int cell = l >> 1, hf = l & 1;
        const int rA = cell + (hf << 5);   // i-row | f-row
        const int rB = rA + 64;            // g-row | o-row
        const float wx0A = Wih0[rA];
        const float wx0B = Wih0[rB];
        const float b0A  = bih0[rA] + bhh0[rA];
        const float b0B  = bih0[rB] + bhh0[rB];
        f32x2 wA2[16], wB2[16];
#pragma unroll
        for (int r = 0; r < 16; ++r) {
            wA2[r][0] = Whh0[rA * 32 + 2 * r]; wA2[r][1] = Whh0[rA * 32 + 2 * r + 1];
            wB2[r][0] = Whh0[rB * 32 + 2 * r]; wB2[r][1] = Whh0[rB * 32 + 2 * r + 1];
        }
        const float kB  = (hf == 0) ? -2.0f : -1.0f;
        const float mB  = (hf == 0) ?  2.0f :  1.0f;
        const float a0B = (hf == 0) ? -1.0f :  0.0f;

        // layer-2 setup (R9 wave-3 roles)
        const int g2 = (l < 48) ? (l >> 2) : 0;
        const int p  = l & 3;
        f32x2 w2p[4];
#pragma unroll
        for (int r = 0; r < 4; ++r) {
            w2p[r][0] = Wih2[g2 * 32 + p * 8 + 2 * r];
            w2p[r][1] = Wih2[g2 * 32 + p * 8 + 2 * r + 1];
        }
        float wr2[3];
#pragma unroll
        for (int r = 0; r < 3; ++r) wr2[r] = Whh2[g2 * 3 + r];
        const float b2 = bih2[g2] + bhh2[g2];
        const bool  g2tanh = (g2 >= 6 && g2 <= 8);
        const float k2  = g2tanh ? -2.0f : -1.0f;
        const float m2  = g2tanh ?  2.0f :  1.0f;
        const float a02 = g2tanh ? -1.0f :  0.0f;

        float c0 = 0.0f, c2 = 0.0f;
        if (hf == 0) { c0 = pre_c0[cell]; h0s[1][SPB - 1][cell] = pre_h0[cell]; }
        if (l < 3) c2 = post_c0[l];
        float h2p0 = post_h0[0], h2p1 = post_h0[1], h2p2 = post_h0[2];
        float h2v = 0.0f;

        // stage x chunk 0
        {
            const int i0 = 4 * l;
            if (i0 < T) {
                const float* xp = x + i0;
                float4 v;
                v.x = xp[0] / 25.0f;
                v.y = (i0 + 1 < T) ? xp[1] / 25.0f : 0.0f;
                v.z = (i0 + 2 < T) ? xp[2] / 25.0f : 0.0f;
                v.w = (i0 + 3 < T) ? xp[3] / 25.0f : 0.0f;
                __builtin_memcpy(&xbuf[0][i0], &v, sizeof(float4));
            }
        }
        __syncthreads();

        for (int e = 0; e < Etot; ++e) {
            // stage next x chunk once per 32 epochs (256 steps)
            if ((e & 31) == 0) {
                const int c = (e >> 5) + 1;
                const int base = c * XCH;
                if (base < T) {
                    const int i0 = base + 4 * l;
                    if (i0 < T) {
                        const float* xp = x + i0;
                        float4 v;
                        v.x = xp[0] / 25.0f;
                        v.y = (i0 + 1 < T) ? xp[1] / 25.0f : 0.0f;
                        v.z = (i0 + 2 < T) ? xp[2] / 25.0f : 0.0f;
                        v.w = (i0 + 3 < T) ? xp[3] / 25.0f : 0.0f;
                        __builtin_memcpy(&xbuf[c & 1][4 * l], &v, sizeof(float4));
                    }
                }
            }
#pragma unroll
            for (int j = 0; j < SPB; ++j) {
                // ---------- layer 0, t = SPB*e + j ----------
                {
                    const int t = SPB * e + j;
                    if (t < T) {
                        const float xn = xbuf[(t >> 8) & 1][t & (XCH - 1)];
                        const float* hp = (j == 0) ? h0s[(e + 1) & 1][SPB - 1]
                                                   : h0s[e & 1][j - 1];
                        f32x2 aA0, aA1, aB0, aB1;
                        aA0[0] = fmaf(xn, wx0A, b0A); aA0[1] = 0.0f;
                        aA1[0] = 0.0f;                aA1[1] = 0.0f;
                        aB0[0] = fmaf(xn, wx0B, b0B); aB0[1] = 0.0f;
                        aB1[0] = 0.0f;                aB1[1] = 0.0f;
#pragma unroll
                        for (int q = 0; q < 8; ++q) {
                            const f32x2 h01 = lds_ld2(&hp[q * 4]);
                            const f32x2 h23 = lds_ld2(&hp[q * 4 + 2]);
                            aA0 = pk_fma(h01, wA2[2 * q],     aA0);
                            aA1 = pk_fma(h23, wA2[2 * q + 1], aA1);
                            aB0 = pk_fma(h01, wB2[2 * q],     aB0);
                            aB1 = pk_fma(h23, wB2[2 * q + 1], aB1);
                        }
                        const float sA = (aA0[0] + aA0[1]) + (aA1[0] + aA1[1]);
                        const float sB = (aB0[0] + aB0[1]) + (aB1[0] + aB1[1]);
                        const float actA = fast_gate(-sA, 1.0f, 0.0f);
                        const float actB = fast_gate(kB * sB, mB, a0B);
                        const float foA = swap1(actA);
                        const float foB = swap1(actB);
                        if (hf == 0) {
                            c0 = fmaf(foA, c0, actA * actB);
                            h0s[e & 1][j][cell] = foB * fast_tanh(c0);
                        }
                    }
                }
                // ---------- layer 2, tt = SPB*(e-2) + j ----------
                if (e >= 2) {
                    const int tt = SPB * (e - 2) + j;
                    if (tt < T) {
                        const float* hp = h1s[e & 1][j];   // (e-2)&1 == e&1
                        f32x2 acc; acc[0] = 0.0f; acc[1] = 0.0f;
                        {
                            const f32x2 a01 = lds_ld2(&hp[p * 8 + 0]);
                            const f32x2 a23 = lds_ld2(&hp[p * 8 + 2]);
                            const f32x2 b01 = lds_ld2(&hp[p * 8 + 4]);
                            const f32x2 b23 = lds_ld2(&hp[p * 8 + 6]);
                            acc = pk_fma(a01, w2p[0], acc);
                            acc = pk_fma(a23, w2p[1], acc);
                            acc = pk_fma(b01, w2p[2], acc);
                            acc = pk_fma(b23, w2p[3], acc);
                        }
                        float a2 = acc[0] + acc[1];
                        a2 += __shfl_xor(a2, 1);
                        a2 += __shfl_xor(a2, 2);
                        const float rec = fmaf(wr2[2], h2p2,
                                          fmaf(wr2[1], h2p1,
                                          fmaf(wr2[0], h2p0, b2)));
                        a2 += rec;
                        const float act2 = fast_gate(k2 * a2, m2, a02);
                        const int lj = (l < 3) ? l : 0;
                        const float i2  = __shfl(act2,  4 * lj);
                        const float f2  = __shfl(act2, 12 + 4 * lj);
                        const float g2v = __shfl(act2, 24 + 4 * lj);
                        const float o2  = __shfl(act2, 36 + 4 * lj);
                        if (l < 3) {
                            c2 = fmaf(f2, c2, i2 * g2v);
                            h2v = o2 * fast_tanh(c2);
                            out[(size_t)tt * 3 + l] = h2v;   // fire-and-forget
                        }
                        h2p0 = __shfl(h2v, 0);
                        h2p1 = __shfl(h2v, 1);
                        h2p2 = __shfl(h2v, 2);
                    }
                }
            }
            pipe_barrier();
        }
    } else {
        // ========== wave 1: full layer 1 (U + V + cell), xor-1 layout ==========
        const int cell = l >> 1, hf = l & 1;
        const int rA = cell + (hf << 5);
        const int rB = rA + 64;
        const float b1A = bih1[rA] + bhh1[rA];
        const float b1B = bih1[rB] + bhh1[rB];
        f32x2 uwA[16], uwB[16], vwA[16], vwB[16];
#pragma unroll
        for (int r = 0; r < 16; ++r) {
            uwA[r][0] = Wih1[rA * 32 + 2 * r]; uwA[r][1] = Wih1[rA * 32 + 2 * r + 1];
            uwB[r][0] = Wih1[rB * 32 + 2 * r]; uwB[r][1] = Wih1[rB * 32 + 2 * r + 1];
            vwA[r][0] = Whh1[rA * 32 + 2 * r]; vwA[r][1] = Whh1[rA * 32 + 2 * r + 1];
            vwB[r][0] = Whh1[rB * 32 + 2 * r]; vwB[r][1] = Whh1[rB * 32 + 2 * r + 1];
        }
        const float kB  = (hf == 0) ? -2.0f : -1.0f;
        const float mB  = (hf == 0) ?  2.0f :  1.0f;
        const float a0B = (hf == 0) ? -1.0f :  0.0f;

        float c1 = 0.0f;
        if (hf == 0) { c1 = pre_c0[32 + cell]; h1s[1][SPB - 1][cell] = pre_h0[32 + cell]; }
        __syncthreads();

        for (int e = 0; e < Etot; ++e) {
            if (e >= 1) {
                const int m = e - 1;                    // time-epoch
#pragma unroll
                for (int j = 0; j < SPB; ++j) {
                    const int t = SPB * m + j;
                    if (t < T) {
                        const float* hp = h0s[m & 1][j];            // h0(t)
                        const float* gp = (j == 0) ? h1s[(m + 1) & 1][SPB - 1]
                                                   : h1s[m & 1][j - 1];   // h1(t-1)
                        // U strands (bias seeded in uA0[0], as R9 wave 1)
                        f32x2 uA0, uA1, uB0, uB1;
                        uA0[0] = b1A;  uA0[1] = 0.0f;
                        uA1[0] = 0.0f; uA1[1] = 0.0f;
                        uB0[0] = 0.0f; uB0[1] = 0.0f;
                        uB1[0] = 0.0f; uB1[1] = 0.0f;
                        // V strands (b1B seeded in vB0[0], as R9 wave 2)
                        f32x2 vA0, vA1, vB0, vB1;
                        vA0[0] = 0.0f; vA0[1] = 0.0f;
                        vA1[0] = 0.0f; vA1[1] = 0.0f;
                        vB0[0] = b1B;  vB0[1] = 0.0f;
                        vB1[0] = 0.0f; vB1[1] = 0.0f;
#pragma unroll
                        for (int q = 0; q < 8; ++q) {
                            const f32x2 h01 = lds_ld2(&hp[q * 4]);
                            const f32x2 h23 = lds_ld2(&hp[q * 4 + 2]);
                            const f32x2 g01 = lds_ld2(&gp[q * 4]);
                            const f32x2 g23 = lds_ld2(&gp[q * 4 + 2]);
                            uA0 = pk_fma(h01, uwA[2 * q],     uA0);
                            uA1 = pk_fma(h23, uwA[2 * q + 1], uA1);
                            uB0 = pk_fma(h01, uwB[2 * q],     uB0);
                            uB1 = pk_fma(h23, uwB[2 * q + 1], uB1);
                            vA0 = pk_fma(g01, vwA[2 * q],     vA0);
                            vA1 = pk_fma(g23, vwA[2 * q + 1], vA1);
                            vB0 = pk_fma(g01, vwB[2 * q],     vB0);
                            vB1 = pk_fma(g23, vwB[2 * q + 1], vB1);
                        }
                        const float UA = (uA0[0] + uA0[1]) + (uA1[0] + uA1[1]);
                        const float UB = (uB0[0] + uB0[1]) + (uB1[0] + uB1[1]);
                        const float sA = UA + ((vA0[0] + vA0[1]) + (vA1[0] + vA1[1]));
                        const float sB = UB + ((vB0[0] + vB0[1]) + (vB1[0] + vB1[1]));
                        const float actA = fast_gate(-sA, 1.0f, 0.0f);
                        const float actB = fast_gate(kB * sB, mB, a0B);
                        const float foA = swap1(actA);
                        const float foB = swap1(actB);
                        if (hf == 0) {
                            c1 = fmaf(foA, c1, actA * actB);
                            h1s[m & 1][j][cell] = foB * fast_tanh(c1);
                        }
                    }
                }
            }
            pipe_barrier();
        }
    }
}

extern "C" void kernel_launch(void* const* d_in, const int* in_sizes, int n_in,
                              void* d_out, int out_size, void* d_ws, size_t ws_size,
                              hipStream_t stream)
{
    const float* x       = (const float*)d_in[0];
    const float* Wih0    = (const float*)d_in[1];
    const float* Whh0    = (const float*)d_in[2];
    const float* bih0    = (const float*)d_in[3];
    const float* bhh0    = (const float*)d_in[4];
    const float* Wih1    = (const float*)d_in[5];
    const float* Whh1    = (const float*)d_in[6];
    const float* bih1    = (const float*)d_in[7];
    const float* bhh1    = (const float*)d_in[8];
    const float* pre_h0  = (const float*)d_in[9];
    const float* pre_c0  = (const float*)d_in[10];
    const float* Wih2    = (const float*)d_in[11];
    const float* Whh2    = (const float*)d_in[12];
    const float* bih2    = (const float*)d_in[13];
    const float* bhh2    = (const float*)d_in[14];
    const float* post_h0 = (const float*)d_in[15];
    const float* post_c0 = (const float*)d_in[16];

    const int T = in_sizes[0];  // x is [T,1]

    lstm3_fuse2_kernel<<<dim3(1), dim3(128), 0, stream>>>(
        x, Wih0, Whh0, bih0, bhh0, Wih1, Whh1, bih1, bhh1, pre_h0, pre_c0,
        Wih2, Whh2, bih2, bhh2, post_h0, post_c0, (float*)d_out, T);
}

// Round 12
// 71219.989 us; speedup vs baseline: 1.6811x; 1.6811x over previous
//
#include <hip/hip_runtime.h>
#include <cstddef>

// ---------------------------------------------------------------------------
// 3-layer LSTM (1->32->32->3), T=200000 sequential steps.
// 4-wave systolic pipeline on one CU, FOUR timesteps per barrier epoch (R9):
//   wave 0: layer 0           h0(4e..4e+3)        (self-recurrent)
//   wave 1: layer 1 U-part    U(4(e-1)+j), j=0..3 (independent dots, ILP)
//   wave 2: layer 1 V + cell  h1(4(e-2)+j)        (self-recurrent; the pacer)
//   wave 3: layer 2 + output  out(4(e-3)+j) + x chunk staging
// One s_barrier per epoch (lgkmcnt-only drain; out-stores fire-and-forget).
// R11 deltas vs R9 (arithmetic strand order bit-identical):
//   - ds_read_b128 for all dot-loop LDS reads (halve read issue)
//   - fast_gate: raw v_rcp (no Newton) -- compensated v_exp kept
//   - U handoff interleaved: one ds_write_b64 / ds_read_b64 per lane
//   - intra-epoch fences dropped (same-wave DS ops are in-order)
// ---------------------------------------------------------------------------

#define XCH 256  // x chunk elements (power of two)

typedef float f32x2 __attribute__((ext_vector_type(2)));
typedef float f32x4 __attribute__((ext_vector_type(4)));

__device__ __forceinline__ f32x2 pk_fma(f32x2 a, f32x2 b, f32x2 c) {
    f32x2 d;
    asm("v_pk_fma_f32 %0, %1, %2, %3" : "=v"(d) : "v"(a), "v"(b), "v"(c));
    return d;
}
__device__ __forceinline__ f32x4 lds_ld4(const float* p) {
    f32x4 v; __builtin_memcpy(&v, p, sizeof(f32x4)); return v;
}
__device__ __forceinline__ f32x2 lo2(f32x4 v) { f32x2 r; r[0] = v[0]; r[1] = v[1]; return r; }
__device__ __forceinline__ f32x2 hi2(f32x4 v) { f32x2 r; r[0] = v[2]; r[1] = v[3]; return r; }

__device__ __forceinline__ float v_exp2(float x) {
    float r; asm("v_exp_f32 %0, %1" : "=v"(r) : "v"(x)); return r;
}
__device__ __forceinline__ float v_rcp(float x) {
    float r; asm("v_rcp_f32 %0, %1" : "=v"(r) : "v"(x)); return r;
}
// act = m / (1 + exp(z)) + a0; residual-compensated v_exp, raw v_rcp (~1 ulp).
__device__ __forceinline__ float fast_gate(float z, float m, float a0) {
    const float L2E    = 1.44269502162933349609375f;
    const float L2E_LO = 1.9259629911e-8f;
    const float LN2    = 0.69314718055994530942f;
    const float t  = z * L2E;
    const float r  = fmaf(z, L2E, -t);
    const float dt = fmaf(z, L2E_LO, r);
    const float e0 = v_exp2(t);
    const float e  = fmaf(e0, dt * LN2, e0);
    return fmaf(m, v_rcp(1.0f + e), a0);
}
__device__ __forceinline__ float fast_tanh(float c) {
    return fast_gate(-2.0f * c, 2.0f, -1.0f);
}

// neighbor exchange (lane ^ 1): quad_perm DPP (VALU), no DS pipe.
__device__ __forceinline__ float swap1(float v) {
    return __shfl_xor(v, 1);
}

// epoch barrier WITHOUT vmcnt drain
__device__ __forceinline__ void pipe_barrier() {
    asm volatile("s_waitcnt lgkmcnt(0)\n\ts_barrier" ::: "memory");
}

__global__ __launch_bounds__(256, 1)
void lstm3_r11_kernel(const float* __restrict__ x,
                      const float* __restrict__ Wih0, const float* __restrict__ Whh0,
                      const float* __restrict__ bih0, const float* __restrict__ bhh0,
                      const float* __restrict__ Wih1, const float* __restrict__ Whh1,
                      const float* __restrict__ bih1, const float* __restrict__ bhh1,
                      const float* __restrict__ pre_h0, const float* __restrict__ pre_c0,
                      const float* __restrict__ Wih2, const float* __restrict__ Whh2,
                      const float* __restrict__ bih2, const float* __restrict__ bhh2,
                      const float* __restrict__ post_h0, const float* __restrict__ post_c0,
                      float* __restrict__ out, int T)
{
    const int tid = threadIdx.x;
    const int w   = tid >> 6;     // 0=L0, 1=L1-U, 2=L1-V, 3=L2+x
    const int l   = tid & 63;

    __shared__ __align__(16) float h0s[2][4][32];    // [parity][step][cell]
    __shared__ __align__(16) float h1s[2][4][32];
    __shared__ __align__(16) float u1s[2][4][128];   // [parity][step][2*rA + (0:A,1:B)]
    __shared__ __align__(16) float xbuf[2][XCH];

    const int T4   = (T + 3) >> 2;
    const int Etot = T4 + 3;

    if (w == 0) {
        // ===== wave 0: layer 0 (1 -> 32); xor-1 gate layout =====
        const int cell = l >> 1, hf = l & 1;
        const int rA = cell + (hf << 5);   // i-row | f-row
        const int rB = rA + 64;            // g-row | o-row
        const float wx0A = Wih0[rA];
        const float wx0B = Wih0[rB];
        const float b0A  = bih0[rA] + bhh0[rA];
        const float b0B  = bih0[rB] + bhh0[rB];
        f32x2 wA2[16], wB2[16];
#pragma unroll
        for (int r = 0; r < 16; ++r) {
            wA2[r][0] = Whh0[rA * 32 + 2 * r]; wA2[r][1] = Whh0[rA * 32 + 2 * r + 1];
            wB2[r][0] = Whh0[rB * 32 + 2 * r]; wB2[r][1] = Whh0[rB * 32 + 2 * r + 1];
        }
        const float kB  = (hf == 0) ? -2.0f : -1.0f;
        const float mB  = (hf == 0) ?  2.0f :  1.0f;
        const float a0B = (hf == 0) ? -1.0f :  0.0f;

        float c0 = 0.0f;
        if (hf == 0) { c0 = pre_c0[cell]; h0s[1][3][cell] = pre_h0[cell]; }
        __syncthreads();

        for (int e = 0; e < Etot; ++e) {
#pragma unroll
            for (int j = 0; j < 4; ++j) {
                const int t = 4 * e + j;
                if (t < T) {
                    const float xn = xbuf[(t >> 8) & 1][t & (XCH - 1)];
                    const float* hp = (j == 0) ? h0s[(e + 1) & 1][3]
                                               : h0s[e & 1][j - 1];
                    f32x2 aA0, aA1, aB0, aB1;
                    aA0[0] = fmaf(xn, wx0A, b0A); aA0[1] = 0.0f;
                    aA1[0] = 0.0f;                aA1[1] = 0.0f;
                    aB0[0] = fmaf(xn, wx0B, b0B); aB0[1] = 0.0f;
                    aB1[0] = 0.0f;                aB1[1] = 0.0f;
#pragma unroll
                    for (int q = 0; q < 4; ++q) {
                        const f32x4 ha = lds_ld4(&hp[q * 8]);
                        const f32x4 hb = lds_ld4(&hp[q * 8 + 4]);
                        aA0 = pk_fma(lo2(ha), wA2[4 * q],     aA0);
                        aA1 = pk_fma(hi2(ha), wA2[4 * q + 1], aA1);
                        aB0 = pk_fma(lo2(ha), wB2[4 * q],     aB0);
                        aB1 = pk_fma(hi2(ha), wB2[4 * q + 1], aB1);
                        aA0 = pk_fma(lo2(hb), wA2[4 * q + 2], aA0);
                        aA1 = pk_fma(hi2(hb), wA2[4 * q + 3], aA1);
                        aB0 = pk_fma(lo2(hb), wB2[4 * q + 2], aB0);
                        aB1 = pk_fma(hi2(hb), wB2[4 * q + 3], aB1);
                    }
                    const float sA = (aA0[0] + aA0[1]) + (aA1[0] + aA1[1]);
                    const float sB = (aB0[0] + aB0[1]) + (aB1[0] + aB1[1]);
                    const float actA = fast_gate(-sA, 1.0f, 0.0f);
                    const float actB = fast_gate(kB * sB, mB, a0B);
                    const float foA = swap1(actA);
                    const float foB = swap1(actB);
                    if (hf == 0) {
                        c0 = fmaf(foA, c0, actA * actB);
                        h0s[e & 1][j][cell] = foB * fast_tanh(c0);
                    }
                }
            }
            pipe_barrier();
        }
    } else if (w == 1) {
        // ===== wave 1: layer 1 U = Wih1 * h0 (4 independent dots) =====
        const int gA = l, gB = l + 64;
        const float b1A = bih1[gA] + bhh1[gA];
        f32x2 wA2[16], wB2[16];
#pragma unroll
        for (int r = 0; r < 16; ++r) {
            wA2[r][0] = Wih1[gA * 32 + 2 * r]; wA2[r][1] = Wih1[gA * 32 + 2 * r + 1];
            wB2[r][0] = Wih1[gB * 32 + 2 * r]; wB2[r][1] = Wih1[gB * 32 + 2 * r + 1];
        }
        __syncthreads();

        for (int e = 0; e < Etot; ++e) {
            if (e >= 1) {
#pragma unroll
                for (int j = 0; j < 4; ++j) {
                    const int t = 4 * (e - 1) + j;
                    if (t < T) {
                        const float* hp = h0s[(e - 1) & 1][j];
                        f32x2 uA0, uA1, uB0, uB1;
                        uA0[0] = b1A;  uA0[1] = 0.0f;
                        uA1[0] = 0.0f; uA1[1] = 0.0f;
                        uB0[0] = 0.0f; uB0[1] = 0.0f;
                        uB1[0] = 0.0f; uB1[1] = 0.0f;
#pragma unroll
                        for (int q = 0; q < 4; ++q) {
                            const f32x4 ha = lds_ld4(&hp[q * 8]);
                            const f32x4 hb = lds_ld4(&hp[q * 8 + 4]);
                            uA0 = pk_fma(lo2(ha), wA2[4 * q],     uA0);
                            uA1 = pk_fma(hi2(ha), wA2[4 * q + 1], uA1);
                            uB0 = pk_fma(lo2(ha), wB2[4 * q],     uB0);
                            uB1 = pk_fma(hi2(ha), wB2[4 * q + 1], uB1);
                            uA0 = pk_fma(lo2(hb), wA2[4 * q + 2], uA0);
                            uA1 = pk_fma(hi2(hb), wA2[4 * q + 3], uA1);
                            uB0 = pk_fma(lo2(hb), wB2[4 * q + 2], uB0);
                            uB1 = pk_fma(hi2(hb), wB2[4 * q + 3], uB1);
                        }
                        // interleaved (row l -> pos 2l, row l+64 -> pos 2l+1)
                        f32x2 up;
                        up[0] = (uA0[0] + uA0[1]) + (uA1[0] + uA1[1]);
                        up[1] = (uB0[0] + uB0[1]) + (uB1[0] + uB1[1]);
                        __builtin_memcpy(&u1s[e & 1][j][2 * l], &up, sizeof(f32x2));
                    }
                }
            }
            pipe_barrier();
        }
    } else if (w == 2) {
        // ===== wave 2: layer 1 V + cell (the pacer); xor-1 layout =====
        const int cell = l >> 1, hf = l & 1;
        const int rA = cell + (hf << 5);
        const int rB = rA + 64;
        const float b1B = bih1[rB] + bhh1[rB];
        f32x2 wA2[16], wB2[16];
#pragma unroll
        for (int r = 0; r < 16; ++r) {
            wA2[r][0] = Whh1[rA * 32 + 2 * r]; wA2[r][1] = Whh1[rA * 32 + 2 * r + 1];
            wB2[r][0] = Whh1[rB * 32 + 2 * r]; wB2[r][1] = Whh1[rB * 32 + 2 * r + 1];
        }
        const float kB  = (hf == 0) ? -2.0f : -1.0f;
        const float mB  = (hf == 0) ?  2.0f :  1.0f;
        const float a0B = (hf == 0) ? -1.0f :  0.0f;

        float c1 = 0.0f;
        if (hf == 0) { c1 = pre_c0[32 + cell]; h1s[1][3][cell] = pre_h0[32 + cell]; }
        __syncthreads();

        for (int e = 0; e < Etot; ++e) {
            if (e >= 2) {
#pragma unroll
                for (int j = 0; j < 4; ++j) {
                    const int t = 4 * (e - 2) + j;
                    if (t < T) {
                        f32x2 Up;                 // one b64 read: U[rA], U[rB]
                        __builtin_memcpy(&Up, &u1s[(e - 1) & 1][j][2 * rA], sizeof(f32x2));
                        const float* gp = (j == 0) ? h1s[(e + 1) & 1][3]
                                                   : h1s[e & 1][j - 1];
                        f32x2 vA0, vA1, vB0, vB1;
                        vA0[0] = 0.0f; vA0[1] = 0.0f;
                        vA1[0] = 0.0f; vA1[1] = 0.0f;
                        vB0[0] = b1B;  vB0[1] = 0.0f;
                        vB1[0] = 0.0f; vB1[1] = 0.0f;
#pragma unroll
                        for (int q = 0; q < 4; ++q) {
                            const f32x4 ga = lds_ld4(&gp[q * 8]);
                            const f32x4 gb = lds_ld4(&gp[q * 8 + 4]);
                            vA0 = pk_fma(lo2(ga), wA2[4 * q],     vA0);
                            vA1 = pk_fma(hi2(ga), wA2[4 * q + 1], vA1);
                            vB0 = pk_fma(lo2(ga), wB2[4 * q],     vB0);
                            vB1 = pk_fma(hi2(ga), wB2[4 * q + 1], vB1);
                            vA0 = pk_fma(lo2(gb), wA2[4 * q + 2], vA0);
                            vA1 = pk_fma(hi2(gb), wA2[4 * q + 3], vA1);
                            vB0 = pk_fma(lo2(gb), wB2[4 * q + 2], vB0);
                            vB1 = pk_fma(hi2(gb), wB2[4 * q + 3], vB1);
                        }
                        const float sA = Up[0] + ((vA0[0] + vA0[1]) + (vA1[0] + vA1[1]));
                        const float sB = Up[1] + ((vB0[0] + vB0[1]) + (vB1[0] + vB1[1]));
                        const float actA = fast_gate(-sA, 1.0f, 0.0f);
                        const float actB = fast_gate(kB * sB, mB, a0B);
                        const float foA = swap1(actA);
                        const float foB = swap1(actB);
                        if (hf == 0) {
                            c1 = fmaf(foA, c1, actA * actB);
                            h1s[e & 1][j][cell] = foB * fast_tanh(c1);
                        }
                    }
                }
            }
            pipe_barrier();
        }
    } else {
        // ===== wave 3: layer 2 (32 -> 3) + output; x chunk staging =====
        const int g2 = (l < 48) ? (l >> 2) : 0;
        const int p  = l & 3;
        f32x2 w2p[4];
#pragma unroll
        for (int r = 0; r < 4; ++r) {
            w2p[r][0] = Wih2[g2 * 32 + p * 8 + 2 * r];
            w2p[r][1] = Wih2[g2 * 32 + p * 8 + 2 * r + 1];
        }
        float wr2[3];
#pragma unroll
        for (int r = 0; r < 3; ++r) wr2[r] = Whh2[g2 * 3 + r];
        const float b2 = bih2[g2] + bhh2[g2];
        const bool  g2tanh = (g2 >= 6 && g2 <= 8);
        const float k2  = g2tanh ? -2.0f : -1.0f;
        const float m2  = g2tanh ?  2.0f :  1.0f;
        const float a02 = g2tanh ? -1.0f :  0.0f;

        float c2 = 0.0f;
        if (l < 3) c2 = post_c0[l];
        float h2p0 = post_h0[0], h2p1 = post_h0[1], h2p2 = post_h0[2];
        float h2v = 0.0f;

        // stage x chunk 0
        {
            const int i0 = 4 * l;
            if (i0 < T) {
                const float* xp = x + i0;
                float4 v;
                v.x = xp[0] / 25.0f;
                v.y = (i0 + 1 < T) ? xp[1] / 25.0f : 0.0f;
                v.z = (i0 + 2 < T) ? xp[2] / 25.0f : 0.0f;
                v.w = (i0 + 3 < T) ? xp[3] / 25.0f : 0.0f;
                __builtin_memcpy(&xbuf[0][i0], &v, sizeof(float4));
            }
        }
        __syncthreads();

        for (int e = 0; e < Etot; ++e) {
            // stage next chunk once per 64 epochs (256 steps)
            if ((e & 63) == 0) {
                const int c = (e >> 6) + 1;
                const int base = c * XCH;
                if (base < T) {
                    const int i0 = base + 4 * l;
                    if (i0 < T) {
                        const float* xp = x + i0;
                        float4 v;
                        v.x = xp[0] / 25.0f;
                        v.y = (i0 + 1 < T) ? xp[1] / 25.0f : 0.0f;
                        v.z = (i0 + 2 < T) ? xp[2] / 25.0f : 0.0f;
                        v.w = (i0 + 3 < T) ? xp[3] / 25.0f : 0.0f;
                        __builtin_memcpy(&xbuf[c & 1][4 * l], &v, sizeof(float4));
                    }
                }
            }
            if (e >= 3) {
#pragma unroll
                for (int j = 0; j < 4; ++j) {
                    const int t = 4 * (e - 3) + j;
                    if (t < T) {
                        const float* hp = h1s[(e - 1) & 1][j];
                        f32x2 acc; acc[0] = 0.0f; acc[1] = 0.0f;
                        {
                            const f32x4 ha = lds_ld4(&hp[p * 8 + 0]);
                            const f32x4 hb = lds_ld4(&hp[p * 8 + 4]);
                            acc = pk_fma(lo2(ha), w2p[0], acc);
                            acc = pk_fma(hi2(ha), w2p[1], acc);
                            acc = pk_fma(lo2(hb), w2p[2], acc);
                            acc = pk_fma(hi2(hb), w2p[3], acc);
                        }
                        float a2 = acc[0] + acc[1];
                        a2 += __shfl_xor(a2, 1);
                        a2 += __shfl_xor(a2, 2);
                        const float rec = fmaf(wr2[2], h2p2,
                                          fmaf(wr2[1], h2p1,
                                          fmaf(wr2[0], h2p0, b2)));
                        a2 += rec;
                        const float act2 = fast_gate(k2 * a2, m2, a02);
                        const int lj = (l < 3) ? l : 0;
                        const float i2  = __shfl(act2,  4 * lj);
                        const float f2  = __shfl(act2, 12 + 4 * lj);
                        const float g2v = __shfl(act2, 24 + 4 * lj);
                        const float o2  = __shfl(act2, 36 + 4 * lj);
                        if (l < 3) {
                            c2 = fmaf(f2, c2, i2 * g2v);
                            h2v = o2 * fast_tanh(c2);
                            out[(size_t)t * 3 + l] = h2v;   // fire-and-forget
                        }
                        h2p0 = __shfl(h2v, 0);
                        h2p1 = __shfl(h2v, 1);
                        h2p2 = __shfl(h2v, 2);
                    }
                }
            }
            pipe_barrier();
        }
    }
}

extern "C" void kernel_launch(void* const* d_in, const int* in_sizes, int n_in,
                              void* d_out, int out_size, void* d_ws, size_t ws_size,
                              hipStream_t stream)
{
    const float* x       = (const float*)d_in[0];
    const float* Wih0    = (const float*)d_in[1];
    const float* Whh0    = (const float*)d_in[2];
    const float* bih0    = (const float*)d_in[3];
    const float* bhh0    = (const float*)d_in[4];
    const float* Wih1    = (const float*)d_in[5];
    const float* Whh1    = (const float*)d_in[6];
    const float* bih1    = (const float*)d_in[7];
    const float* bhh1    = (const float*)d_in[8];
    const float* pre_h0  = (const float*)d_in[9];
    const float* pre_c0  = (const float*)d_in[10];
    const float* Wih2    = (const float*)d_in[11];
    const float* Whh2    = (const float*)d_in[12];
    const float* bih2    = (const float*)d_in[13];
    const float* bhh2    = (const float*)d_in[14];
    const float* post_h0 = (const float*)d_in[15];
    const float* post_c0 = (const float*)d_in[16];

    const int T = in_sizes[0];  // x is [T,1]

    lstm3_r11_kernel<<<dim3(1), dim3(256), 0, stream>>>(
        x, Wih0, Whh0, bih0, bhh0, Wih1, Whh1, bih1, bhh1, pre_h0, pre_c0,
        Wih2, Whh2, bih2, bhh2, post_h0, post_c0, (float*)d_out, T);
}

// Round 13
// 57502.850 us; speedup vs baseline: 2.0822x; 1.2385x over previous
//
#include <hip/hip_runtime.h>
#include <cstddef>

// ---------------------------------------------------------------------------
// 3-layer LSTM (1->32->32->3), T=200000 sequential steps.
// 4-wave systolic pipeline on one CU, EIGHT timesteps per barrier epoch:
//   wave 0: layer 0           h0(8e..8e+7)        (self-recurrent)
//   wave 1: layer 1 U-part    U(8(e-1)+j)         (independent dots, ILP)
//   wave 2: layer 1 V + cell  h1(8(e-2)+j)        (self-recurrent; the pacer)
//   wave 3: layer 2 + output  out(8(e-3)+j) + x chunk staging
// One s_barrier per epoch (lgkmcnt-only drain; out-stores fire-and-forget).
// R12 deltas vs R11 (bit-identical arithmetic):
//   - SPB 4 -> 8 (barrier amortization x2)
//   - waves 0/1/2 run guard-free past T (garbage steps stay in LDS rings;
//     only wave 3's out[] store is masked at t < T)
//   - activation arg pre-scaled: t = x * (k*L2E) with k*L2E exact for
//     k in {-1,-2} -- same rounding as ((k*x)*L2E), one mul less per act
//   - wave 2 issues h1(t-1) reads before the U read (latency-first order)
// ---------------------------------------------------------------------------

#define XCH 256  // x chunk elements
#define SPB 8    // steps per barrier epoch

typedef float f32x2 __attribute__((ext_vector_type(2)));
typedef float f32x4 __attribute__((ext_vector_type(4)));

__device__ __forceinline__ f32x2 pk_fma(f32x2 a, f32x2 b, f32x2 c) {
    f32x2 d;
    asm("v_pk_fma_f32 %0, %1, %2, %3" : "=v"(d) : "v"(a), "v"(b), "v"(c));
    return d;
}
__device__ __forceinline__ f32x4 lds_ld4(const float* p) {
    f32x4 v; __builtin_memcpy(&v, p, sizeof(f32x4)); return v;
}
__device__ __forceinline__ f32x2 lo2(f32x4 v) { f32x2 r; r[0] = v[0]; r[1] = v[1]; return r; }
__device__ __forceinline__ f32x2 hi2(f32x4 v) { f32x2 r; r[0] = v[2]; r[1] = v[3]; return r; }

__device__ __forceinline__ float v_exp2(float x) {
    float r; asm("v_exp_f32 %0, %1" : "=v"(r) : "v"(x)); return r;
}
__device__ __forceinline__ float v_rcp(float x) {
    float r; asm("v_rcp_f32 %0, %1" : "=v"(r) : "v"(x)); return r;
}
// act = m / (1 + exp(k*x)) + a0 with kl2e = k*log2e (exact for k=+-1,+-2),
// kl2e_lo the matching low part. Residual-compensated v_exp, raw v_rcp.
__device__ __forceinline__ float fast_gate_k(float x, float kl2e, float kl2e_lo,
                                             float m, float a0) {
    const float LN2 = 0.69314718055994530942f;
    const float t  = x * kl2e;
    const float r  = fmaf(x, kl2e, -t);
    const float dt = fmaf(x, kl2e_lo, r);
    const float e0 = v_exp2(t);
    const float e  = fmaf(e0, dt * LN2, e0);
    return fmaf(m, v_rcp(1.0f + e), a0);
}
// tanh(c) = 2/(1+exp(-2c)) - 1
#define KT   (-2.88539004325866699218750f)   // -2*L2E (exact)
#define KT_LO (-3.8519259822e-8f)            // -2*L2E_LO (exact)
__device__ __forceinline__ float fast_tanh(float c) {
    return fast_gate_k(c, KT, KT_LO, 2.0f, -1.0f);
}
#define K1   (-1.44269502162933349609375f)   // -L2E
#define K1_LO (-1.9259629911e-8f)

// neighbor exchange (lane ^ 1): quad_perm DPP (VALU), no DS pipe.
__device__ __forceinline__ float swap1(float v) {
    return __shfl_xor(v, 1);
}

// epoch barrier WITHOUT vmcnt drain
__device__ __forceinline__ void pipe_barrier() {
    asm volatile("s_waitcnt lgkmcnt(0)\n\ts_barrier" ::: "memory");
}

__global__ __launch_bounds__(256, 1)
void lstm3_r12_kernel(const float* __restrict__ x,
                      const float* __restrict__ Wih0, const float* __restrict__ Whh0,
                      const float* __restrict__ bih0, const float* __restrict__ bhh0,
                      const float* __restrict__ Wih1, const float* __restrict__ Whh1,
                      const float* __restrict__ bih1, const float* __restrict__ bhh1,
                      const float* __restrict__ pre_h0, const float* __restrict__ pre_c0,
                      const float* __restrict__ Wih2, const float* __restrict__ Whh2,
                      const float* __restrict__ bih2, const float* __restrict__ bhh2,
                      const float* __restrict__ post_h0, const float* __restrict__ post_c0,
                      float* __restrict__ out, int T)
{
    const int tid = threadIdx.x;
    const int w   = tid >> 6;     // 0=L0, 1=L1-U, 2=L1-V, 3=L2+x
    const int l   = tid & 63;

    __shared__ __align__(16) float h0s[2][SPB][32];
    __shared__ __align__(16) float h1s[2][SPB][32];
    __shared__ __align__(16) float u1s[2][SPB][128];  // [..][2*rA + (0:A,1:B)]
    __shared__ __align__(16) float xbuf[2][XCH];

    const int T8   = (T + SPB - 1) / SPB;
    const int Etot = T8 + 3;

    if (w == 0) {
        // ===== wave 0: layer 0 (1 -> 32); xor-1 gate layout =====
        const int cell = l >> 1, hf = l & 1;
        const int rA = cell + (hf << 5);
        const int rB = rA + 64;
        const float wx0A = Wih0[rA];
        const float wx0B = Wih0[rB];
        const float b0A  = bih0[rA] + bhh0[rA];
        const float b0B  = bih0[rB] + bhh0[rB];
        f32x2 wA2[16], wB2[16];
#pragma unroll
        for (int r = 0; r < 16; ++r) {
            wA2[r][0] = Whh0[rA * 32 + 2 * r]; wA2[r][1] = Whh0[rA * 32 + 2 * r + 1];
            wB2[r][0] = Whh0[rB * 32 + 2 * r]; wB2[r][1] = Whh0[rB * 32 + 2 * r + 1];
        }
        const float klB   = (hf == 0) ? KT    : K1;
        const float klBlo = (hf == 0) ? KT_LO : K1_LO;
        const float mB    = (hf == 0) ?  2.0f :  1.0f;
        const float a0B   = (hf == 0) ? -1.0f :  0.0f;

        float c0 = 0.0f;
        if (hf == 0) { c0 = pre_c0[cell]; h0s[1][SPB - 1][cell] = pre_h0[cell]; }
        __syncthreads();

        for (int e = 0; e < Etot; ++e) {
#pragma unroll
            for (int j = 0; j < SPB; ++j) {
                const int t = SPB * e + j;
                const float xn = xbuf[(t >> 8) & 1][t & (XCH - 1)];
                const float* hp = (j == 0) ? h0s[(e + 1) & 1][SPB - 1]
                                           : h0s[e & 1][j - 1];
                f32x2 aA0, aA1, aB0, aB1;
                aA0[0] = fmaf(xn, wx0A, b0A); aA0[1] = 0.0f;
                aA1[0] = 0.0f;                aA1[1] = 0.0f;
                aB0[0] = fmaf(xn, wx0B, b0B); aB0[1] = 0.0f;
                aB1[0] = 0.0f;                aB1[1] = 0.0f;
#pragma unroll
                for (int q = 0; q < 4; ++q) {
                    const f32x4 ha = lds_ld4(&hp[q * 8]);
                    const f32x4 hb = lds_ld4(&hp[q * 8 + 4]);
                    aA0 = pk_fma(lo2(ha), wA2[4 * q],     aA0);
                    aA1 = pk_fma(hi2(ha), wA2[4 * q + 1], aA1);
                    aB0 = pk_fma(lo2(ha), wB2[4 * q],     aB0);
                    aB1 = pk_fma(hi2(ha), wB2[4 * q + 1], aB1);
                    aA0 = pk_fma(lo2(hb), wA2[4 * q + 2], aA0);
                    aA1 = pk_fma(hi2(hb), wA2[4 * q + 3], aA1);
                    aB0 = pk_fma(lo2(hb), wB2[4 * q + 2], aB0);
                    aB1 = pk_fma(hi2(hb), wB2[4 * q + 3], aB1);
                }
                const float sA = (aA0[0] + aA0[1]) + (aA1[0] + aA1[1]);
                const float sB = (aB0[0] + aB0[1]) + (aB1[0] + aB1[1]);
                const float actA = fast_gate_k(sA, K1, K1_LO, 1.0f, 0.0f);
                const float actB = fast_gate_k(sB, klB, klBlo, mB, a0B);
                const float foA = swap1(actA);
                const float foB = swap1(actB);
                if (hf == 0) {
                    c0 = fmaf(foA, c0, actA * actB);
                    h0s[e & 1][j][cell] = foB * fast_tanh(c0);
                }
            }
            pipe_barrier();
        }
    } else if (w == 1) {
        // ===== wave 1: layer 1 U = Wih1 * h0 (8 independent dots) =====
        const int gA = l, gB = l + 64;
        const float b1A = bih1[gA] + bhh1[gA];
        f32x2 wA2[16], wB2[16];
#pragma unroll
        for (int r = 0; r < 16; ++r) {
            wA2[r][0] = Wih1[gA * 32 + 2 * r]; wA2[r][1] = Wih1[gA * 32 + 2 * r + 1];
            wB2[r][0] = Wih1[gB * 32 + 2 * r]; wB2[r][1] = Wih1[gB * 32 + 2 * r + 1];
        }
        __syncthreads();

        for (int e = 0; e < Etot; ++e) {
            if (e >= 1) {
#pragma unroll
                for (int j = 0; j < SPB; ++j) {
                    const float* hp = h0s[(e - 1) & 1][j];
                    f32x2 uA0, uA1, uB0, uB1;
                    uA0[0] = b1A;  uA0[1] = 0.0f;
                    uA1[0] = 0.0f; uA1[1] = 0.0f;
                    uB0[0] = 0.0f; uB0[1] = 0.0f;
                    uB1[0] = 0.0f; uB1[1] = 0.0f;
#pragma unroll
                    for (int q = 0; q < 4; ++q) {
                        const f32x4 ha = lds_ld4(&hp[q * 8]);
                        const f32x4 hb = lds_ld4(&hp[q * 8 + 4]);
                        uA0 = pk_fma(lo2(ha), wA2[4 * q],     uA0);
                        uA1 = pk_fma(hi2(ha), wA2[4 * q + 1], uA1);
                        uB0 = pk_fma(lo2(ha), wB2[4 * q],     uB0);
                        uB1 = pk_fma(hi2(ha), wB2[4 * q + 1], uB1);
                        uA0 = pk_fma(lo2(hb), wA2[4 * q + 2], uA0);
                        uA1 = pk_fma(hi2(hb), wA2[4 * q + 3], uA1);
                        uB0 = pk_fma(lo2(hb), wB2[4 * q + 2], uB0);
                        uB1 = pk_fma(hi2(hb), wB2[4 * q + 3], uB1);
                    }
                    f32x2 up;
                    up[0] = (uA0[0] + uA0[1]) + (uA1[0] + uA1[1]);
                    up[1] = (uB0[0] + uB0[1]) + (uB1[0] + uB1[1]);
                    __builtin_memcpy(&u1s[e & 1][j][2 * l], &up, sizeof(f32x2));
                }
            }
            pipe_barrier();
        }
    } else if (w == 2) {
        // ===== wave 2: layer 1 V + cell (the pacer); xor-1 layout =====
        const int cell = l >> 1, hf = l & 1;
        const int rA = cell + (hf << 5);
        const int rB = rA + 64;
        const float b1B = bih1[rB] + bhh1[rB];
        f32x2 wA2[16], wB2[16];
#pragma unroll
        for (int r = 0; r < 16; ++r) {
            wA2[r][0] = Whh1[rA * 32 + 2 * r]; wA2[r][1] = Whh1[rA * 32 + 2 * r + 1];
            wB2[r][0] = Whh1[rB * 32 + 2 * r]; wB2[r][1] = Whh1[rB * 32 + 2 * r + 1];
        }
        const float klB   = (hf == 0) ? KT    : K1;
        const float klBlo = (hf == 0) ? KT_LO : K1_LO;
        const float mB    = (hf == 0) ?  2.0f :  1.0f;
        const float a0B   = (hf == 0) ? -1.0f :  0.0f;

        float c1 = 0.0f;
        if (hf == 0) { c1 = pre_c0[32 + cell]; h1s[1][SPB - 1][cell] = pre_h0[32 + cell]; }
        __syncthreads();

        for (int e = 0; e < Etot; ++e) {
            if (e >= 2) {
#pragma unroll
                for (int j = 0; j < SPB; ++j) {
                    const float* gp = (j == 0) ? h1s[(e + 1) & 1][SPB - 1]
                                               : h1s[e & 1][j - 1];
                    // latency-critical reads first
                    const f32x4 ga0 = lds_ld4(&gp[0]);
                    const f32x4 gb0 = lds_ld4(&gp[4]);
                    f32x2 Up;
                    __builtin_memcpy(&Up, &u1s[(e - 1) & 1][j][2 * rA], sizeof(f32x2));
                    f32x2 vA0, vA1, vB0, vB1;
                    vA0[0] = 0.0f; vA0[1] = 0.0f;
                    vA1[0] = 0.0f; vA1[1] = 0.0f;
                    vB0[0] = b1B;  vB0[1] = 0.0f;
                    vB1[0] = 0.0f; vB1[1] = 0.0f;
                    vA0 = pk_fma(lo2(ga0), wA2[0], vA0);
                    vA1 = pk_fma(hi2(ga0), wA2[1], vA1);
                    vB0 = pk_fma(lo2(ga0), wB2[0], vB0);
                    vB1 = pk_fma(hi2(ga0), wB2[1], vB1);
                    vA0 = pk_fma(lo2(gb0), wA2[2], vA0);
                    vA1 = pk_fma(hi2(gb0), wA2[3], vA1);
                    vB0 = pk_fma(lo2(gb0), wB2[2], vB0);
                    vB1 = pk_fma(hi2(gb0), wB2[3], vB1);
#pragma unroll
                    for (int q = 1; q < 4; ++q) {
                        const f32x4 ga = lds_ld4(&gp[q * 8]);
                        const f32x4 gb = lds_ld4(&gp[q * 8 + 4]);
                        vA0 = pk_fma(lo2(ga), wA2[4 * q],     vA0);
                        vA1 = pk_fma(hi2(ga), wA2[4 * q + 1], vA1);
                        vB0 = pk_fma(lo2(ga), wB2[4 * q],     vB0);
                        vB1 = pk_fma(hi2(ga), wB2[4 * q + 1], vB1);
                        vA0 = pk_fma(lo2(gb), wA2[4 * q + 2], vA0);
                        vA1 = pk_fma(hi2(gb), wA2[4 * q + 3], vA1);
                        vB0 = pk_fma(lo2(gb), wB2[4 * q + 2], vB0);
                        vB1 = pk_fma(hi2(gb), wB2[4 * q + 3], vB1);
                    }
                    const float sA = Up[0] + ((vA0[0] + vA0[1]) + (vA1[0] + vA1[1]));
                    const float sB = Up[1] + ((vB0[0] + vB0[1]) + (vB1[0] + vB1[1]));
                    const float actA = fast_gate_k(sA, K1, K1_LO, 1.0f, 0.0f);
                    const float actB = fast_gate_k(sB, klB, klBlo, mB, a0B);
                    const float foA = swap1(actA);
                    const float foB = swap1(actB);
                    if (hf == 0) {
                        c1 = fmaf(foA, c1, actA * actB);
                        h1s[e & 1][j][cell] = foB * fast_tanh(c1);
                    }
                }
            }
            pipe_barrier();
        }
    } else {
        // ===== wave 3: layer 2 (32 -> 3) + output; x chunk staging =====
        const int g2 = (l < 48) ? (l >> 2) : 0;
        const int p  = l & 3;
        f32x2 w2p[4];
#pragma unroll
        for (int r = 0; r < 4; ++r) {
            w2p[r][0] = Wih2[g2 * 32 + p * 8 + 2 * r];
            w2p[r][1] = Wih2[g2 * 32 + p * 8 + 2 * r + 1];
        }
        float wr2[3];
#pragma unroll
        for (int r = 0; r < 3; ++r) wr2[r] = Whh2[g2 * 3 + r];
        const float b2 = bih2[g2] + bhh2[g2];
        const bool  g2tanh = (g2 >= 6 && g2 <= 8);
        const float kl2   = g2tanh ? KT    : K1;
        const float kl2lo = g2tanh ? KT_LO : K1_LO;
        const float m2    = g2tanh ?  2.0f :  1.0f;
        const float a02   = g2tanh ? -1.0f :  0.0f;

        float c2 = 0.0f;
        if (l < 3) c2 = post_c0[l];
        float h2p0 = post_h0[0], h2p1 = post_h0[1], h2p2 = post_h0[2];
        float h2v = 0.0f;

        // stage x chunk 0
        {
            const int i0 = 4 * l;
            if (i0 < T) {
                const float* xp = x + i0;
                float4 v;
                v.x = xp[0] / 25.0f;
                v.y = (i0 + 1 < T) ? xp[1] / 25.0f : 0.0f;
                v.z = (i0 + 2 < T) ? xp[2] / 25.0f : 0.0f;
                v.w = (i0 + 3 < T) ? xp[3] / 25.0f : 0.0f;
                __builtin_memcpy(&xbuf[0][i0], &v, sizeof(float4));
            }
        }
        __syncthreads();

        for (int e = 0; e < Etot; ++e) {
            // stage next chunk once per 32 epochs (256 steps)
            if ((e & 31) == 0) {
                const int c = (e >> 5) + 1;
                const int base = c * XCH;
                if (base < T) {
                    const int i0 = base + 4 * l;
                    if (i0 < T) {
                        const float* xp = x + i0;
                        float4 v;
                        v.x = xp[0] / 25.0f;
                        v.y = (i0 + 1 < T) ? xp[1] / 25.0f : 0.0f;
                        v.z = (i0 + 2 < T) ? xp[2] / 25.0f : 0.0f;
                        v.w = (i0 + 3 < T) ? xp[3] / 25.0f : 0.0f;
                        __builtin_memcpy(&xbuf[c & 1][4 * l], &v, sizeof(float4));
                    }
                }
            }
            if (e >= 3) {
#pragma unroll
                for (int j = 0; j < SPB; ++j) {
                    const int t = SPB * (e - 3) + j;
                    const float* hp = h1s[(e - 1) & 1][j];
                    f32x2 acc; acc[0] = 0.0f; acc[1] = 0.0f;
                    {
                        const f32x4 ha = lds_ld4(&hp[p * 8 + 0]);
                        const f32x4 hb = lds_ld4(&hp[p * 8 + 4]);
                        acc = pk_fma(lo2(ha), w2p[0], acc);
                        acc = pk_fma(hi2(ha), w2p[1], acc);
                        acc = pk_fma(lo2(hb), w2p[2], acc);
                        acc = pk_fma(hi2(hb), w2p[3], acc);
                    }
                    float a2 = acc[0] + acc[1];
                    a2 += __shfl_xor(a2, 1);
                    a2 += __shfl_xor(a2, 2);
                    const float rec = fmaf(wr2[2], h2p2,
                                      fmaf(wr2[1], h2p1,
                                      fmaf(wr2[0], h2p0, b2)));
                    a2 += rec;
                    const float act2 = fast_gate_k(a2, kl2, kl2lo, m2, a02);
                    const int lj = (l < 3) ? l : 0;
                    const float i2  = __shfl(act2,  4 * lj);
                    const float f2  = __shfl(act2, 12 + 4 * lj);
                    const float g2v = __shfl(act2, 24 + 4 * lj);
                    const float o2  = __shfl(act2, 36 + 4 * lj);
                    if (l < 3) {
                        c2 = fmaf(f2, c2, i2 * g2v);
                        h2v = o2 * fast_tanh(c2);
                        if (t < T) out[(size_t)t * 3 + l] = h2v;  // masked store
                    }
                    h2p0 = __shfl(h2v, 0);
                    h2p1 = __shfl(h2v, 1);
                    h2p2 = __shfl(h2v, 2);
                }
            }
            pipe_barrier();
        }
    }
}

extern "C" void kernel_launch(void* const* d_in, const int* in_sizes, int n_in,
                              void* d_out, int out_size, void* d_ws, size_t ws_size,
                              hipStream_t stream)
{
    const float* x       = (const float*)d_in[0];
    const float* Wih0    = (const float*)d_in[1];
    const float* Whh0    = (const float*)d_in[2];
    const float* bih0    = (const float*)d_in[3];
    const float* bhh0    = (const float*)d_in[4];
    const float* Wih1    = (const float*)d_in[5];
    const float* Whh1    = (const float*)d_in[6];
    const float* bih1    = (const float*)d_in[7];
    const float* bhh1    = (const float*)d_in[8];
    const float* pre_h0  = (const float*)d_in[9];
    const float* pre_c0  = (const float*)d_in[10];
    const float* Wih2    = (const float*)d_in[11];
    const float* Whh2    = (const float*)d_in[12];
    const float* bih2    = (const float*)d_in[13];
    const float* bhh2    = (const float*)d_in[14];
    const float* post_h0 = (const float*)d_in[15];
    const float* post_c0 = (const float*)d_in[16];

    const int T = in_sizes[0];  // x is [T,1]

    lstm3_r12_kernel<<<dim3(1), dim3(256), 0, stream>>>(
        x, Wih0, Whh0, bih0, bhh0, Wih1, Whh1, bih1, bhh1, pre_h0, pre_c0,
        Wih2, Whh2, bih2, bhh2, post_h0, post_c0, (float*)d_out, T);
}

// Round 15
// 56427.612 us; speedup vs baseline: 2.1218x; 1.0191x over previous
//
#include <hip/hip_runtime.h>
#include <cstddef>

// ---------------------------------------------------------------------------
// 3-layer LSTM (1->32->32->3), T=200000 sequential steps.
// 4-wave systolic pipeline on one CU, EIGHT timesteps per barrier epoch:
//   wave 0: layer 0           h0(8e..8e+7)        (self-recurrent pacer)
//   wave 1: layer 1 U-part    U(8(e-1)+j)         (independent dots, ILP)
//   wave 2: layer 1 V + cell  h1(8(e-2)+j)        (self-recurrent pacer)
//   wave 3: layer 2 + output  out(8(e-3)+j) + x chunk staging
// One s_barrier per epoch (lgkmcnt-only drain; out-stores fire-and-forget).
// R14 = R13 with the DPP direction fixed: lane i <- lane i+N is row_SHL:N
// (0x100+N), not row_shr (0x110+N, which is lane i <- lane i-N and zeroed
// the L2 gate exchange -> out was identically 0 in R13).
// R13 deltas vs R12: 8-strand dots on waves 0/2 (dep chain halved);
// fused h = fmaf(2o, sigmoid(2c), -o); U/x reads hoisted to epoch top;
// wave 3 lanes 0-11 own one L2 gate row each, exchange via DPP row_shl.
// ---------------------------------------------------------------------------

#define XCH 256  // x chunk elements
#define SPB 8    // steps per barrier epoch

typedef float f32x2 __attribute__((ext_vector_type(2)));
typedef float f32x4 __attribute__((ext_vector_type(4)));

__device__ __forceinline__ f32x2 pk_fma(f32x2 a, f32x2 b, f32x2 c) {
    f32x2 d;
    asm("v_pk_fma_f32 %0, %1, %2, %3" : "=v"(d) : "v"(a), "v"(b), "v"(c));
    return d;
}
__device__ __forceinline__ f32x4 lds_ld4(const float* p) {
    f32x4 v; __builtin_memcpy(&v, p, sizeof(f32x4)); return v;
}
__device__ __forceinline__ f32x2 lo2(f32x4 v) { f32x2 r; r[0] = v[0]; r[1] = v[1]; return r; }
__device__ __forceinline__ f32x2 hi2(f32x4 v) { f32x2 r; r[0] = v[2]; r[1] = v[3]; return r; }

__device__ __forceinline__ float v_exp2(float x) {
    float r; asm("v_exp_f32 %0, %1" : "=v"(r) : "v"(x)); return r;
}
__device__ __forceinline__ float v_rcp(float x) {
    float r; asm("v_rcp_f32 %0, %1" : "=v"(r) : "v"(x)); return r;
}

#define LN2F  0.69314718055994530942f
#define KT    (-2.88539004325866699218750f)   // -2*log2e (exact 2x)
#define KT_LO (-3.8519259822e-8f)
#define K1    (-1.44269502162933349609375f)   // -log2e
#define K1_LO (-1.9259629911e-8f)

// act = m / (1 + exp(k*x)) + a0, kl2e = k*log2e exact; compensated v_exp.
__device__ __forceinline__ float fast_gate_k(float x, float kl2e, float kl2e_lo,
                                             float m, float a0) {
    const float t  = x * kl2e;
    const float r  = fmaf(x, kl2e, -t);
    const float dt = fmaf(x, kl2e_lo, r);
    const float e0 = v_exp2(t);
    const float e  = fmaf(e0, dt * LN2F, e0);
    return fmaf(m, v_rcp(1.0f + e), a0);
}
// o * tanh(c) = fma(2o, s, -o), s = sigmoid(2c); 2o/-o overlap the exp.
__device__ __forceinline__ float o_tanh(float o, float c) {
    const float t  = c * KT;
    const float r  = fmaf(c, KT, -t);
    const float dt = fmaf(c, KT_LO, r);
    const float e0 = v_exp2(t);
    const float e  = fmaf(e0, dt * LN2F, e0);
    const float s  = v_rcp(1.0f + e);
    return fmaf(o + o, s, -o);
}

// neighbor exchange (lane ^ 1): quad_perm DPP.
__device__ __forceinline__ float swap1(float v) {
    return __shfl_xor(v, 1);
}
// lane i <- lane i+N within 16-lane rows: DPP row_SHL:N (0x100+N).
template <int N>
__device__ __forceinline__ float lane_plusN(float v) {
#if __has_builtin(__builtin_amdgcn_update_dpp)
    int i = __builtin_bit_cast(int, v);
    i = __builtin_amdgcn_update_dpp(0, i, 0x100 + N, 0xF, 0xF, false);
    return __builtin_bit_cast(float, i);
#else
    return __shfl_down(v, N);
#endif
}

// epoch barrier WITHOUT vmcnt drain
__device__ __forceinline__ void pipe_barrier() {
    asm volatile("s_waitcnt lgkmcnt(0)\n\ts_barrier" ::: "memory");
}

__global__ __launch_bounds__(256, 1)
void lstm3_r14_kernel(const float* __restrict__ x,
                      const float* __restrict__ Wih0, const float* __restrict__ Whh0,
                      const float* __restrict__ bih0, const float* __restrict__ bhh0,
                      const float* __restrict__ Wih1, const float* __restrict__ Whh1,
                      const float* __restrict__ bih1, const float* __restrict__ bhh1,
                      const float* __restrict__ pre_h0, const float* __restrict__ pre_c0,
                      const float* __restrict__ Wih2, const float* __restrict__ Whh2,
                      const float* __restrict__ bih2, const float* __restrict__ bhh2,
                      const float* __restrict__ post_h0, const float* __restrict__ post_c0,
                      float* __restrict__ out, int T)
{
    const int tid = threadIdx.x;
    const int w   = tid >> 6;     // 0=L0, 1=L1-U, 2=L1-V, 3=L2+x
    const int l   = tid & 63;

    __shared__ __align__(16) float h0s[2][SPB][32];
    __shared__ __align__(16) float h1s[2][SPB][32];
    __shared__ __align__(16) float u1s[2][SPB][128];  // [..][2*rA + (0:A,1:B)]
    __shared__ __align__(16) float xbuf[2][XCH];

    const int T8   = (T + SPB - 1) / SPB;
    const int Etot = T8 + 3;

    if (w == 0) {
        // ===== wave 0: layer 0 (1 -> 32); xor-1 gate layout =====
        const int cell = l >> 1, hf = l & 1;
        const int rA = cell + (hf << 5);
        const int rB = rA + 64;
        const float wx0A = Wih0[rA];
        const float wx0B = Wih0[rB];
        const float b0A  = bih0[rA] + bhh0[rA];
        const float b0B  = bih0[rB] + bhh0[rB];
        f32x2 wA2[16], wB2[16];
#pragma unroll
        for (int r = 0; r < 16; ++r) {
            wA2[r][0] = Whh0[rA * 32 + 2 * r]; wA2[r][1] = Whh0[rA * 32 + 2 * r + 1];
            wB2[r][0] = Whh0[rB * 32 + 2 * r]; wB2[r][1] = Whh0[rB * 32 + 2 * r + 1];
        }
        const float klB   = (hf == 0) ? KT    : K1;
        const float klBlo = (hf == 0) ? KT_LO : K1_LO;
        const float mB    = (hf == 0) ?  2.0f :  1.0f;
        const float a0B   = (hf == 0) ? -1.0f :  0.0f;

        float c0 = 0.0f;
        if (hf == 0) { c0 = pre_c0[cell]; h0s[1][SPB - 1][cell] = pre_h0[cell]; }
        __syncthreads();

        for (int e = 0; e < Etot; ++e) {
            // hoist this epoch's 8 x values (aligned, one chunk)
            const int t0 = SPB * e;
            const float* xp = &xbuf[(t0 >> 8) & 1][t0 & (XCH - 1)];
            const f32x4 xa = lds_ld4(xp);
            const f32x4 xb = lds_ld4(xp + 4);
#pragma unroll
            for (int j = 0; j < SPB; ++j) {
                const float xn = (j < 4) ? xa[j] : xb[j - 4];
                const float* hp = (j == 0) ? h0s[(e + 1) & 1][SPB - 1]
                                           : h0s[e & 1][j - 1];
                f32x2 aA[4], aB[4];
                aA[0][0] = fmaf(xn, wx0A, b0A); aA[0][1] = 0.0f;
                aB[0][0] = fmaf(xn, wx0B, b0B); aB[0][1] = 0.0f;
#pragma unroll
                for (int s = 1; s < 4; ++s) { aA[s][0] = 0.0f; aA[s][1] = 0.0f;
                                              aB[s][0] = 0.0f; aB[s][1] = 0.0f; }
#pragma unroll
                for (int q = 0; q < 4; ++q) {
                    const f32x4 ha = lds_ld4(&hp[q * 8]);
                    const f32x4 hb = lds_ld4(&hp[q * 8 + 4]);
                    aA[0] = pk_fma(lo2(ha), wA2[4 * q],     aA[0]);
                    aA[1] = pk_fma(hi2(ha), wA2[4 * q + 1], aA[1]);
                    aA[2] = pk_fma(lo2(hb), wA2[4 * q + 2], aA[2]);
                    aA[3] = pk_fma(hi2(hb), wA2[4 * q + 3], aA[3]);
                    aB[0] = pk_fma(lo2(ha), wB2[4 * q],     aB[0]);
                    aB[1] = pk_fma(hi2(ha), wB2[4 * q + 1], aB[1]);
                    aB[2] = pk_fma(lo2(hb), wB2[4 * q + 2], aB[2]);
                    aB[3] = pk_fma(hi2(hb), wB2[4 * q + 3], aB[3]);
                }
                const f32x2 sAv = (aA[0] + aA[1]) + (aA[2] + aA[3]);
                const f32x2 sBv = (aB[0] + aB[1]) + (aB[2] + aB[3]);
                const float sA = sAv[0] + sAv[1];
                const float sB = sBv[0] + sBv[1];
                const float actA = fast_gate_k(sA, K1, K1_LO, 1.0f, 0.0f);
                const float actB = fast_gate_k(sB, klB, klBlo, mB, a0B);
                const float foA = swap1(actA);
                const float foB = swap1(actB);
                if (hf == 0) {
                    c0 = fmaf(foA, c0, actA * actB);
                    h0s[e & 1][j][cell] = o_tanh(foB, c0);
                }
            }
            pipe_barrier();
        }
    } else if (w == 1) {
        // ===== wave 1: layer 1 U = Wih1 * h0 (8 independent dots) =====
        const int gA = l, gB = l + 64;
        const float b1A = bih1[gA] + bhh1[gA];
        f32x2 wA2[16], wB2[16];
#pragma unroll
        for (int r = 0; r < 16; ++r) {
            wA2[r][0] = Wih1[gA * 32 + 2 * r]; wA2[r][1] = Wih1[gA * 32 + 2 * r + 1];
            wB2[r][0] = Wih1[gB * 32 + 2 * r]; wB2[r][1] = Wih1[gB * 32 + 2 * r + 1];
        }
        __syncthreads();

        for (int e = 0; e < Etot; ++e) {
            if (e >= 1) {
#pragma unroll
                for (int j = 0; j < SPB; ++j) {
                    const float* hp = h0s[(e - 1) & 1][j];
                    f32x2 uA0, uA1, uB0, uB1;
                    uA0[0] = b1A;  uA0[1] = 0.0f;
                    uA1[0] = 0.0f; uA1[1] = 0.0f;
                    uB0[0] = 0.0f; uB0[1] = 0.0f;
                    uB1[0] = 0.0f; uB1[1] = 0.0f;
#pragma unroll
                    for (int q = 0; q < 4; ++q) {
                        const f32x4 ha = lds_ld4(&hp[q * 8]);
                        const f32x4 hb = lds_ld4(&hp[q * 8 + 4]);
                        uA0 = pk_fma(lo2(ha), wA2[4 * q],     uA0);
                        uA1 = pk_fma(hi2(ha), wA2[4 * q + 1], uA1);
                        uB0 = pk_fma(lo2(ha), wB2[4 * q],     uB0);
                        uB1 = pk_fma(hi2(ha), wB2[4 * q + 1], uB1);
                        uA0 = pk_fma(lo2(hb), wA2[4 * q + 2], uA0);
                        uA1 = pk_fma(hi2(hb), wA2[4 * q + 3], uA1);
                        uB0 = pk_fma(lo2(hb), wB2[4 * q + 2], uB0);
                        uB1 = pk_fma(hi2(hb), wB2[4 * q + 3], uB1);
                    }
                    f32x2 up;
                    up[0] = (uA0[0] + uA0[1]) + (uA1[0] + uA1[1]);
                    up[1] = (uB0[0] + uB0[1]) + (uB1[0] + uB1[1]);
                    __builtin_memcpy(&u1s[e & 1][j][2 * l], &up, sizeof(f32x2));
                }
            }
            pipe_barrier();
        }
    } else if (w == 2) {
        // ===== wave 2: layer 1 V + cell (the pacer); xor-1 layout =====
        const int cell = l >> 1, hf = l & 1;
        const int rA = cell + (hf << 5);
        const int rB = rA + 64;
        const float b1B = bih1[rB] + bhh1[rB];
        f32x2 wA2[16], wB2[16];
#pragma unroll
        for (int r = 0; r < 16; ++r) {
            wA2[r][0] = Whh1[rA * 32 + 2 * r]; wA2[r][1] = Whh1[rA * 32 + 2 * r + 1];
            wB2[r][0] = Whh1[rB * 32 + 2 * r]; wB2[r][1] = Whh1[rB * 32 + 2 * r + 1];
        }
        const float klB   = (hf == 0) ? KT    : K1;
        const float klBlo = (hf == 0) ? KT_LO : K1_LO;
        const float mB    = (hf == 0) ?  2.0f :  1.0f;
        const float a0B   = (hf == 0) ? -1.0f :  0.0f;

        float c1 = 0.0f;
        if (hf == 0) { c1 = pre_c0[32 + cell]; h1s[1][SPB - 1][cell] = pre_h0[32 + cell]; }
        __syncthreads();

        for (int e = 0; e < Etot; ++e) {
            if (e >= 2) {
                // hoist all 8 U reads (written by wave 1 last epoch)
                f32x2 Up[SPB];
#pragma unroll
                for (int j = 0; j < SPB; ++j)
                    __builtin_memcpy(&Up[j], &u1s[(e - 1) & 1][j][2 * rA], sizeof(f32x2));
#pragma unroll
                for (int j = 0; j < SPB; ++j) {
                    const float* gp = (j == 0) ? h1s[(e + 1) & 1][SPB - 1]
                                               : h1s[e & 1][j - 1];
                    f32x2 vA[4], vB[4];
                    vB[0][0] = b1B;  vB[0][1] = 0.0f;
                    vA[0][0] = 0.0f; vA[0][1] = 0.0f;
#pragma unroll
                    for (int s = 1; s < 4; ++s) { vA[s][0] = 0.0f; vA[s][1] = 0.0f;
                                                  vB[s][0] = 0.0f; vB[s][1] = 0.0f; }
#pragma unroll
                    for (int q = 0; q < 4; ++q) {
                        const f32x4 ga = lds_ld4(&gp[q * 8]);
                        const f32x4 gb = lds_ld4(&gp[q * 8 + 4]);
                        vA[0] = pk_fma(lo2(ga), wA2[4 * q],     vA[0]);
                        vA[1] = pk_fma(hi2(ga), wA2[4 * q + 1], vA[1]);
                        vA[2] = pk_fma(lo2(gb), wA2[4 * q + 2], vA[2]);
                        vA[3] = pk_fma(hi2(gb), wA2[4 * q + 3], vA[3]);
                        vB[0] = pk_fma(lo2(ga), wB2[4 * q],     vB[0]);
                        vB[1] = pk_fma(hi2(ga), wB2[4 * q + 1], vB[1]);
                        vB[2] = pk_fma(lo2(gb), wB2[4 * q + 2], vB[2]);
                        vB[3] = pk_fma(hi2(gb), wB2[4 * q + 3], vB[3]);
                    }
                    const f32x2 sAv = (vA[0] + vA[1]) + (vA[2] + vA[3]);
                    const f32x2 sBv = (vB[0] + vB[1]) + (vB[2] + vB[3]);
                    const float sA = Up[j][0] + (sAv[0] + sAv[1]);
                    const float sB = Up[j][1] + (sBv[0] + sBv[1]);
                    const float actA = fast_gate_k(sA, K1, K1_LO, 1.0f, 0.0f);
                    const float actB = fast_gate_k(sB, klB, klBlo, mB, a0B);
                    const float foA = swap1(actA);
                    const float foB = swap1(actB);
                    if (hf == 0) {
                        c1 = fmaf(foA, c1, actA * actB);
                        h1s[e & 1][j][cell] = o_tanh(foB, c1);
                    }
                }
            }
            pipe_barrier();
        }
    } else {
        // ===== wave 3: layer 2 (32 -> 3) + output; x chunk staging =====
        // lanes 0..11 each own one gate row g = l (i:0-2, f:3-5, g:6-8, o:9-11)
        const int g = (l < 12) ? l : 0;
        f32x2 w2[16];
#pragma unroll
        for (int r = 0; r < 16; ++r) {
            w2[r][0] = Wih2[g * 32 + 2 * r];
            w2[r][1] = Wih2[g * 32 + 2 * r + 1];
        }
        float wr2[3];
#pragma unroll
        for (int r = 0; r < 3; ++r) wr2[r] = Whh2[g * 3 + r];
        const float b2 = bih2[g] + bhh2[g];
        const bool  gt = (g >= 6 && g <= 8);
        const float kl2   = gt ? KT    : K1;
        const float kl2lo = gt ? KT_LO : K1_LO;
        const float m2    = gt ?  2.0f :  1.0f;
        const float a02   = gt ? -1.0f :  0.0f;

        float c2 = 0.0f;
        if (l < 3) c2 = post_c0[l];
        float h2p0 = post_h0[0], h2p1 = post_h0[1], h2p2 = post_h0[2];
        float h2v = 0.0f;

        // stage x chunk 0
        {
            const int i0 = 4 * l;
            if (i0 < T) {
                const float* xp = x + i0;
                float4 v;
                v.x = xp[0] / 25.0f;
                v.y = (i0 + 1 < T) ? xp[1] / 25.0f : 0.0f;
                v.z = (i0 + 2 < T) ? xp[2] / 25.0f : 0.0f;
                v.w = (i0 + 3 < T) ? xp[3] / 25.0f : 0.0f;
                __builtin_memcpy(&xbuf[0][i0], &v, sizeof(float4));
            }
        }
        __syncthreads();

        for (int e = 0; e < Etot; ++e) {
            // stage next chunk once per 32 epochs (256 steps)
            if ((e & 31) == 0) {
                const int c = (e >> 5) + 1;
                const int base = c * XCH;
                if (base < T) {
                    const int i0 = base + 4 * l;
                    if (i0 < T) {
                        const float* xp = x + i0;
                        float4 v;
                        v.x = xp[0] / 25.0f;
                        v.y = (i0 + 1 < T) ? xp[1] / 25.0f : 0.0f;
                        v.z = (i0 + 2 < T) ? xp[2] / 25.0f : 0.0f;
                        v.w = (i0 + 3 < T) ? xp[3] / 25.0f : 0.0f;
                        __builtin_memcpy(&xbuf[c & 1][4 * l], &v, sizeof(float4));
                    }
                }
            }
            if (e >= 3) {
#pragma unroll
                for (int j = 0; j < SPB; ++j) {
                    const int t = SPB * (e - 3) + j;
                    const float* hp = h1s[(e - 1) & 1][j];
                    f32x2 ac[4];
#pragma unroll
                    for (int s = 0; s < 4; ++s) { ac[s][0] = 0.0f; ac[s][1] = 0.0f; }
#pragma unroll
                    for (int q = 0; q < 4; ++q) {
                        const f32x4 ha = lds_ld4(&hp[q * 8]);
                        const f32x4 hb = lds_ld4(&hp[q * 8 + 4]);
                        ac[0] = pk_fma(lo2(ha), w2[4 * q],     ac[0]);
                        ac[1] = pk_fma(hi2(ha), w2[4 * q + 1], ac[1]);
                        ac[2] = pk_fma(lo2(hb), w2[4 * q + 2], ac[2]);
                        ac[3] = pk_fma(hi2(hb), w2[4 * q + 3], ac[3]);
                    }
                    const f32x2 sv = (ac[0] + ac[1]) + (ac[2] + ac[3]);
                    float a2 = sv[0] + sv[1];
                    a2 += fmaf(wr2[2], h2p2,
                          fmaf(wr2[1], h2p1,
                          fmaf(wr2[0], h2p0, b2)));
                    const float act2 = fast_gate_k(a2, kl2, kl2lo, m2, a02);
                    const float f2  = lane_plusN<3>(act2);   // f-gate of own cell
                    const float g2v = lane_plusN<6>(act2);   // g-gate
                    const float o2  = lane_plusN<9>(act2);   // o-gate
                    if (l < 3) {
                        c2 = fmaf(f2, c2, act2 * g2v);       // i2 = own act2
                        h2v = o_tanh(o2, c2);
                        if (t < T) out[(size_t)t * 3 + l] = h2v;  // masked store
                    }
                    h2p0 = __shfl(h2v, 0);
                    h2p1 = __shfl(h2v, 1);
                    h2p2 = __shfl(h2v, 2);
                }
            }
            pipe_barrier();
        }
    }
}

extern "C" void kernel_launch(void* const* d_in, const int* in_sizes, int n_in,
                              void* d_out, int out_size, void* d_ws, size_t ws_size,
                              hipStream_t stream)
{
    const float* x       = (const float*)d_in[0];
    const float* Wih0    = (const float*)d_in[1];
    const float* Whh0    = (const float*)d_in[2];
    const float* bih0    = (const float*)d_in[3];
    const float* bhh0    = (const float*)d_in[4];
    const float* Wih1    = (const float*)d_in[5];
    const float* Whh1    = (const float*)d_in[6];
    const float* bih1    = (const float*)d_in[7];
    const float* bhh1    = (const float*)d_in[8];
    const float* pre_h0  = (const float*)d_in[9];
    const float* pre_c0  = (const float*)d_in[10];
    const float* Wih2    = (const float*)d_in[11];
    const float* Whh2    = (const float*)d_in[12];
    const float* bih2    = (const float*)d_in[13];
    const float* bhh2    = (const float*)d_in[14];
    const float* post_h0 = (const float*)d_in[15];
    const float* post_c0 = (const float*)d_in[16];

    const int T = in_sizes[0];  // x is [T,1]

    lstm3_r14_kernel<<<dim3(1), dim3(256), 0, stream>>>(
        x, Wih0, Whh0, bih0, bhh0, Wih1, Whh1, bih1, bhh1, pre_h0, pre_c0,
        Wih2, Whh2, bih2, bhh2, post_h0, post_c0, (float*)d_out, T);
}